// Round 2
// baseline (9553.588 us; speedup 1.0000x reference)
//
#include <hip/hip_runtime.h>
#include <hip/hip_bf16.h>

#define DS 32
#define DIM 512
#define NH 8
#define HD 64
#define NE 4
#define NC 2
#define BB 8
#define LL 2
#define FFD 2048
#define S2 1024
#define SS 1028
#define MM (BB*SS)          // 8224 rows total

// ---------------- embed: h[b,i,:] = (i<4) ? x : patch_embed ----------------
__global__ void embed_kernel(const float* __restrict__ x, const float* __restrict__ patches,
                             const float* __restrict__ We, const float* __restrict__ be,
                             float* __restrict__ h) {
    int row = blockIdx.x;                 // 0..MM-1
    int b = row / SS, i = row % SS;
    float* hr = h + (size_t)row * DIM;
    if (i < NE) {
        const float* xr = x + (size_t)b*NE*DIM + (size_t)i*DIM;
        for (int d = threadIdx.x; d < DIM; d += blockDim.x) hr[d] = xr[d];
    } else {
        int p = i - NE;
        float c0 = patches[(size_t)b*3*S2 + 0*S2 + p];
        float c1 = patches[(size_t)b*3*S2 + 1*S2 + p];
        float c2 = patches[(size_t)b*3*S2 + 2*S2 + p];
        for (int d = threadIdx.x; d < DIM; d += blockDim.x)
            hr[d] = be[d] + c0*We[d] + c1*We[DIM+d] + c2*We[2*DIM+d];
    }
}

// ---------------- layernorm over last dim (512), one block per row ----------------
__global__ void ln_kernel(const float* __restrict__ in, float* __restrict__ out,
                          const float* __restrict__ g, const float* __restrict__ bt) {
    int row = blockIdx.x;
    const float* xr = in + (size_t)row*DIM;
    int t = threadIdx.x;
    float v0 = xr[t], v1 = xr[t+256];
    float s = v0 + v1, s2 = v0*v0 + v1*v1;
    for (int off = 32; off; off >>= 1) { s += __shfl_down(s, off); s2 += __shfl_down(s2, off); }
    __shared__ float ps[4], ps2[4];
    int wid = t >> 6, lane = t & 63;
    if (lane == 0) { ps[wid] = s; ps2[wid] = s2; }
    __syncthreads();
    if (t == 0) { ps[0] = ps[0]+ps[1]+ps[2]+ps[3]; ps2[0] = ps2[0]+ps2[1]+ps2[2]+ps2[3]; }
    __syncthreads();
    float mean = ps[0] * (1.0f/DIM);
    float var  = ps2[0] * (1.0f/DIM) - mean*mean;
    float inv = rsqrtf(var + 1e-5f);
    float* orow = out + (size_t)row*DIM;
    orow[t]     = (v0 - mean)*inv*g[t]     + bt[t];
    orow[t+256] = (v1 - mean)*inv*g[t+256] + bt[t+256];
}

// ---------------- f32 GEMM: C = op(A@W + bias)*scale (+res). 128x128 tile, 8x8/thread ----------------
__global__ __launch_bounds__(256) void gemm128(const float* __restrict__ A, const float* __restrict__ W,
                        const float* __restrict__ bias, const float* __restrict__ res,
                        float* __restrict__ C, int M, int N, int K, float scale, int relu) {
    __shared__ __align__(16) float As[8][132];
    __shared__ __align__(16) float Bs[8][132];
    int row0 = blockIdx.x*128, col0 = blockIdx.y*128;
    int tid = threadIdx.x;
    int tx = tid & 15, ty = tid >> 4;
    float acc[8][8];
    #pragma unroll
    for (int i = 0; i < 8; i++)
        #pragma unroll
        for (int j = 0; j < 8; j++) acc[i][j] = 0.f;

    for (int k0 = 0; k0 < K; k0 += 8) {
        #pragma unroll
        for (int i = 0; i < 4; i++) {
            int e = tid + i*256; int r = e >> 3, kk = e & 7;
            int gr = row0 + r;
            As[kk][r] = (gr < M) ? A[(size_t)gr*K + k0 + kk] : 0.f;
        }
        #pragma unroll
        for (int i = 0; i < 4; i++) {
            int e = tid + i*256; int kk = e >> 7, n = e & 127;
            Bs[kk][n] = W[(size_t)(k0+kk)*N + col0 + n];
        }
        __syncthreads();
        #pragma unroll
        for (int kk = 0; kk < 8; kk++) {
            float4 a0 = *(const float4*)&As[kk][ty*8];
            float4 a1 = *(const float4*)&As[kk][ty*8+4];
            float4 b0 = *(const float4*)&Bs[kk][tx*8];
            float4 b1 = *(const float4*)&Bs[kk][tx*8+4];
            float a[8] = {a0.x,a0.y,a0.z,a0.w,a1.x,a1.y,a1.z,a1.w};
            float bb[8] = {b0.x,b0.y,b0.z,b0.w,b1.x,b1.y,b1.z,b1.w};
            #pragma unroll
            for (int i = 0; i < 8; i++)
                #pragma unroll
                for (int j = 0; j < 8; j++) acc[i][j] += a[i]*bb[j];
        }
        __syncthreads();
    }
    #pragma unroll
    for (int ii = 0; ii < 8; ii++) {
        int r = row0 + ty*8 + ii;
        if (r >= M) continue;
        size_t rb = (size_t)r*N;
        #pragma unroll
        for (int jj = 0; jj < 8; jj++) {
            int c = col0 + tx*8 + jj;
            float val = (acc[ii][jj] + bias[c]) * scale;
            if (relu) val = fmaxf(val, 0.f);
            if (res)  val += res[rb + c];
            C[rb + c] = val;
        }
    }
}

// ---------------- qx/qy: qx[bh,pi,t] = q[b,NE+pi,h,:]·x_emb[t,:] ----------------
__global__ void qxy_kernel(const float* __restrict__ q, const float* __restrict__ x_emb,
                           const float* __restrict__ y_emb, float* __restrict__ qx,
                           float* __restrict__ qy) {
    int id = blockIdx.x;                  // (b*NH+h)*S2 + pi
    int pi = id & (S2-1);
    int bh = id >> 10;
    int b = bh >> 3, hh = bh & 7;
    __shared__ float qs[HD];
    if (threadIdx.x < HD)
        qs[threadIdx.x] = q[((size_t)(b*SS + NE + pi))*DIM + hh*HD + threadIdx.x];
    __syncthreads();
    int t = threadIdx.x & 63;
    const float* emb = (threadIdx.x < 64) ? x_emb : y_emb;
    float acc = 0.f;
    #pragma unroll 8
    for (int d = 0; d < HD; d++) acc += qs[d] * emb[t*HD + d];
    float* dst = (threadIdx.x < 64) ? qx : qy;
    dst[(size_t)id*64 + t] = acc;
}

// ---------------- qp: qp0/1[bh,i] = q[b,i,h,:]·pad0/1 ----------------
__global__ void qp_kernel(const float* __restrict__ q, const float* __restrict__ pad0,
                          const float* __restrict__ pad1, float* __restrict__ qp0,
                          float* __restrict__ qp1) {
    int idx = blockIdx.x * blockDim.x + threadIdx.x;   // over BB*NH*SS
    if (idx >= BB*NH*SS) return;
    int i = idx % SS; int bh = idx / SS; int b = bh >> 3, hh = bh & 7;
    const float* qr = q + ((size_t)(b*SS + i))*DIM + hh*HD;
    float a0 = 0.f, a1 = 0.f;
    #pragma unroll 8
    for (int d = 0; d < HD; d++) { float qv = qr[d]; a0 += qv*pad0[d]; a1 += qv*pad1[d]; }
    qp0[idx] = a0; qp1[idx] = a1;
}

// ---------------- attention: two-pass, 8 query rows per block ----------------
#define ITILE 8
#define NTILE 129   // ceil(1028/8)
__global__ __launch_bounds__(256) void attn_kernel(
    const float* __restrict__ q, const float* __restrict__ k, const float* __restrict__ v,
    const float* __restrict__ qx, const float* __restrict__ qy,
    const float* __restrict__ qp0, const float* __restrict__ qp1,
    float* __restrict__ o) {
    __shared__ float sc[ITILE][SS];              // 32.9 KB
    __shared__ __align__(16) float qs[ITILE][HD];
    __shared__ __align__(16) float kt[128][68];  // 34.8 KB
    int tile = blockIdx.x % NTILE;
    int bh   = blockIdx.x / NTILE;               // b*NH + h
    int b = bh >> 3, hh = bh & 7;
    int i0 = tile * ITILE;
    int tid = threadIdx.x;
    int ty = tid >> 6, tx = tid & 63;            // wave id, lane

    for (int e = tid; e < ITILE*HD; e += 256) {
        int ii = e >> 6, d = e & 63;
        int i = i0 + ii;
        qs[ii][d] = (i < SS) ? q[((size_t)(b*SS+i))*DIM + hh*HD + d] : 0.f;
    }
    __syncthreads();

    int r0 = ty*2, r1 = ty*2+1;
    int gi0 = i0 + r0, gi1 = i0 + r1;

    // pass 1: scores (content + gathered pos bias), chunks of 128 keys
    for (int j0 = 0; j0 < SS; j0 += 128) {
        #pragma unroll
        for (int i2 = 0; i2 < 8; i2++) {
            int e = tid + i2*256;                // 0..2047
            int r = e >> 4, dc = (e & 15)*4;
            int j = j0 + r;
            float4 val = make_float4(0.f,0.f,0.f,0.f);
            if (j < SS) val = *(const float4*)&k[((size_t)(b*SS+j))*DIM + hh*HD + dc];
            *(float4*)&kt[r][dc] = val;
        }
        __syncthreads();
        float a00=0.f, a01=0.f, a10=0.f, a11=0.f;
        #pragma unroll
        for (int d = 0; d < HD; d += 4) {
            float4 k0 = *(const float4*)&kt[tx][d];
            float4 k1 = *(const float4*)&kt[tx+64][d];
            float4 q0 = *(const float4*)&qs[r0][d];
            float4 q1 = *(const float4*)&qs[r1][d];
            a00 += q0.x*k0.x + q0.y*k0.y + q0.z*k0.z + q0.w*k0.w;
            a01 += q0.x*k1.x + q0.y*k1.y + q0.z*k1.z + q0.w*k1.w;
            a10 += q1.x*k0.x + q1.y*k0.y + q1.z*k0.z + q1.w*k0.w;
            a11 += q1.x*k1.x + q1.y*k1.y + q1.z*k1.z + q1.w*k1.w;
        }
        int jc[2] = { j0 + tx, j0 + tx + 64 };
        float av[2][2] = { {a00, a01}, {a10, a11} };
        int gis[2] = { gi0, gi1 };
        #pragma unroll
        for (int rr = 0; rr < 2; rr++) {
            int i = gis[rr];
            if (i >= SS) continue;
            #pragma unroll
            for (int cc = 0; cc < 2; cc++) {
                int j = jc[cc];
                if (j >= SS) continue;
                float bias;
                if (i < NE) bias = (j < NE) ? qp0[(size_t)bh*SS + i] : qp1[(size_t)bh*SS + i];
                else if (j < NE) bias = qp1[(size_t)bh*SS + i];
                else {
                    int pi = i - NE, pj = j - NE;
                    int xd = (pj & 31) - (pi & 31) + 32;
                    int yd = (pj >> 5) - (pi >> 5) + 32;
                    size_t base = ((size_t)bh*S2 + pi)*64;
                    bias = qx[base + xd] + qy[base + yd];
                }
                sc[r0 + rr][j] = av[rr][cc] + bias;
            }
        }
        __syncthreads();
    }

    // softmax: wave ty owns rows r0,r1
    #pragma unroll
    for (int rr = 0; rr < 2; rr++) {
        int ii = r0 + rr;
        if (i0 + ii >= SS) continue;
        float m = -1e30f;
        for (int jj = tx; jj < SS; jj += 64) m = fmaxf(m, sc[ii][jj]);
        for (int off = 32; off; off >>= 1) m = fmaxf(m, __shfl_xor(m, off));
        float s = 0.f;
        for (int jj = tx; jj < SS; jj += 64) { float e = __expf(sc[ii][jj]-m); sc[ii][jj] = e; s += e; }
        for (int off = 32; off; off >>= 1) s += __shfl_xor(s, off);
        float inv = 1.0f / s;
        for (int jj = tx; jj < SS; jj += 64) sc[ii][jj] *= inv;
    }
    __syncthreads();

    // pass 2: o[ii][d] = sum_j p[ii][j] * v[j][d]; thread: rows r0,r1, col d=tx
    float o0 = 0.f, o1 = 0.f;
    for (int j = 0; j < SS; j += 4) {
        float4 p0 = *(const float4*)&sc[r0][j];
        float4 p1 = *(const float4*)&sc[r1][j];
        const float* vb = v + ((size_t)(b*SS+j))*DIM + hh*HD + tx;
        float v0 = vb[0], v1 = vb[DIM], v2 = vb[2*DIM], v3 = vb[3*DIM];
        o0 += p0.x*v0 + p0.y*v1 + p0.z*v2 + p0.w*v3;
        o1 += p1.x*v0 + p1.y*v1 + p1.z*v2 + p1.w*v3;
    }
    if (gi0 < SS) o[((size_t)(b*SS+gi0))*DIM + hh*HD + tx] = o0;
    if (gi1 < SS) o[((size_t)(b*SS+gi1))*DIM + hh*HD + tx] = o1;
}

// ---------------- classifier + transpose to [B,NC,DS,DS] ----------------
__global__ void cls_kernel(const float* __restrict__ h, const float* __restrict__ Wc,
                           const float* __restrict__ bc, float* __restrict__ out) {
    int g = blockIdx.x*4 + (threadIdx.x >> 6);
    int lane = threadIdx.x & 63;
    if (g >= BB*S2) return;
    int b = g >> 10, p = g & 1023;
    const float* hr = h + ((size_t)(b*SS + NE + p))*DIM;
    float a0 = 0.f, a1 = 0.f;
    for (int d = lane; d < DIM; d += 64) {
        float hv = hr[d];
        a0 += hv * Wc[d*NC + 0];
        a1 += hv * Wc[d*NC + 1];
    }
    for (int off = 32; off; off >>= 1) { a0 += __shfl_down(a0, off); a1 += __shfl_down(a1, off); }
    if (lane == 0) {
        out[((size_t)(b*NC + 0))*S2 + p] = a0 + bc[0];
        out[((size_t)(b*NC + 1))*S2 + p] = a1 + bc[1];
    }
}

extern "C" void kernel_launch(void* const* d_in, const int* in_sizes, int n_in,
                              void* d_out, int out_size, void* d_ws, size_t ws_size,
                              hipStream_t stream) {
    const float* x      = (const float*)d_in[0];
    const float* patches= (const float*)d_in[1];
    const float* We     = (const float*)d_in[2];
    const float* be     = (const float*)d_in[3];
    const float* x_emb  = (const float*)d_in[4];
    const float* y_emb  = (const float*)d_in[5];
    const float* pad0   = (const float*)d_in[6];
    const float* pad1   = (const float*)d_in[7];
    const float* Wq     = (const float*)d_in[8];
    const float* bq     = (const float*)d_in[9];
    const float* Wk     = (const float*)d_in[10];
    const float* bk     = (const float*)d_in[11];
    const float* Wv     = (const float*)d_in[12];
    const float* bv     = (const float*)d_in[13];
    const float* Wo     = (const float*)d_in[14];
    const float* bo     = (const float*)d_in[15];
    const float* ln1_g  = (const float*)d_in[16];
    const float* ln1_b  = (const float*)d_in[17];
    const float* ln2_g  = (const float*)d_in[18];
    const float* ln2_b  = (const float*)d_in[19];
    const float* W1     = (const float*)d_in[20];
    const float* b1     = (const float*)d_in[21];
    const float* W2     = (const float*)d_in[22];
    const float* b2     = (const float*)d_in[23];
    const float* Wc     = (const float*)d_in[24];
    const float* bc     = (const float*)d_in[25];
    float* out = (float*)d_out;

    // workspace layout (floats): needs 8*MD + 2*BB*NH*SS ≈ 33.8M floats ≈ 135.3 MB
    float* ws = (float*)d_ws;
    const size_t MD = (size_t)MM*DIM;
    float* h   = ws;
    float* hn  = ws + MD;
    float* q   = ws + 2*MD;
    float* kx  = ws + 3*MD;
    float* vx  = ws + 4*MD;
    float* o   = ws + 5*MD;
    float* t   = ws + 2*MD;          // FFN scratch aliases q,kx,vx,o (dead by then); M*FF = 4*MD
    float* qx  = ws + 6*MD;
    float* qy  = ws + 7*MD;
    float* qp0 = ws + 8*MD;
    float* qp1 = qp0 + (size_t)BB*NH*SS;

    const float scale = 0.125f;      // 1/sqrt(64)
    dim3 g512((MM+127)/128, DIM/128);   // (65,4)
    dim3 gFF ((MM+127)/128, FFD/128);   // (65,16)

    embed_kernel<<<MM, 256, 0, stream>>>(x, patches, We, be, h);

    for (int l = 0; l < LL; l++) {
        const float* Wql = Wq + (size_t)l*DIM*DIM; const float* bql = bq + (size_t)l*DIM;
        const float* Wkl = Wk + (size_t)l*DIM*DIM; const float* bkl = bk + (size_t)l*DIM;
        const float* Wvl = Wv + (size_t)l*DIM*DIM; const float* bvl = bv + (size_t)l*DIM;
        const float* Wol = Wo + (size_t)l*DIM*DIM; const float* bol = bo + (size_t)l*DIM;
        const float* W1l = W1 + (size_t)l*DIM*FFD; const float* b1l = b1 + (size_t)l*FFD;
        const float* W2l = W2 + (size_t)l*FFD*DIM; const float* b2l = b2 + (size_t)l*DIM;

        ln_kernel<<<MM, 256, 0, stream>>>(h, hn, ln1_g + l*DIM, ln1_b + l*DIM);
        gemm128<<<g512, 256, 0, stream>>>(hn, Wql, bql, nullptr, q,  MM, DIM, DIM, scale, 0);
        gemm128<<<g512, 256, 0, stream>>>(hn, Wkl, bkl, nullptr, kx, MM, DIM, DIM, 1.f, 0);
        gemm128<<<g512, 256, 0, stream>>>(hn, Wvl, bvl, nullptr, vx, MM, DIM, DIM, 1.f, 0);
        qxy_kernel<<<BB*NH*S2, 128, 0, stream>>>(q, x_emb, y_emb, qx, qy);
        qp_kernel<<<(BB*NH*SS+255)/256, 256, 0, stream>>>(q, pad0, pad1, qp0, qp1);
        attn_kernel<<<BB*NH*NTILE, 256, 0, stream>>>(q, kx, vx, qx, qy, qp0, qp1, o);
        gemm128<<<g512, 256, 0, stream>>>(o, Wol, bol, h, h, MM, DIM, DIM, 1.f, 0);
        ln_kernel<<<MM, 256, 0, stream>>>(h, hn, ln2_g + l*DIM, ln2_b + l*DIM);
        gemm128<<<gFF, 256, 0, stream>>>(hn, W1l, b1l, nullptr, t, MM, FFD, DIM, 1.f, 1);
        gemm128<<<g512, 256, 0, stream>>>(t, W2l, b2l, h, h, MM, DIM, FFD, 1.f, 0);
    }

    cls_kernel<<<(BB*S2)/4, 256, 0, stream>>>(h, Wc, bc, out);
}

// Round 3
// 1484.639 us; speedup vs baseline: 6.4350x; 6.4350x over previous
//
#include <hip/hip_runtime.h>
#include <hip/hip_bf16.h>

#define DS 32
#define DIM 512
#define NH 8
#define HD 64
#define NE 4
#define NC 2
#define BB 8
#define LL 2
#define FFD 2048
#define S2 1024
#define SS 1028
#define MM (BB*SS)          // 8224 rows

typedef __attribute__((ext_vector_type(8))) short s16x8;
typedef __attribute__((ext_vector_type(4))) float f32x4;
typedef unsigned short u16;

__device__ __forceinline__ u16 f2b(float f) {
    __hip_bfloat16 h = __float2bfloat16(f);
    return *reinterpret_cast<u16*>(&h);
}
__device__ __forceinline__ float b2f(u16 u) {
    __hip_bfloat16 h;
    *reinterpret_cast<u16*>(&h) = u;
    return __bfloat162float(h);
}

// ---------------- embed: h[b,i,:] = (i<4) ? x : patch_embed (f32) ----------------
__global__ void embed_kernel(const float* __restrict__ x, const float* __restrict__ patches,
                             const float* __restrict__ We, const float* __restrict__ be,
                             float* __restrict__ h) {
    int row = blockIdx.x;
    int b = row / SS, i = row % SS;
    float* hr = h + (size_t)row * DIM;
    if (i < NE) {
        const float* xr = x + (size_t)b*NE*DIM + (size_t)i*DIM;
        for (int d = threadIdx.x; d < DIM; d += blockDim.x) hr[d] = xr[d];
    } else {
        int p = i - NE;
        float c0 = patches[(size_t)b*3*S2 + 0*S2 + p];
        float c1 = patches[(size_t)b*3*S2 + 1*S2 + p];
        float c2 = patches[(size_t)b*3*S2 + 2*S2 + p];
        for (int d = threadIdx.x; d < DIM; d += blockDim.x)
            hr[d] = be[d] + c0*We[d] + c1*We[DIM+d] + c2*We[2*DIM+d];
    }
}

// ---------------- layernorm: f32 in -> bf16 out ----------------
__global__ void ln_kernel(const float* __restrict__ in, u16* __restrict__ out,
                          const float* __restrict__ g, const float* __restrict__ bt) {
    int row = blockIdx.x;
    const float* xr = in + (size_t)row*DIM;
    int t = threadIdx.x;
    float v0 = xr[t], v1 = xr[t+256];
    float s = v0 + v1, s2 = v0*v0 + v1*v1;
    for (int off = 32; off; off >>= 1) { s += __shfl_down(s, off); s2 += __shfl_down(s2, off); }
    __shared__ float ps[4], ps2[4];
    int wid = t >> 6, lane = t & 63;
    if (lane == 0) { ps[wid] = s; ps2[wid] = s2; }
    __syncthreads();
    if (t == 0) { ps[0] = ps[0]+ps[1]+ps[2]+ps[3]; ps2[0] = ps2[0]+ps2[1]+ps2[2]+ps2[3]; }
    __syncthreads();
    float mean = ps[0] * (1.0f/DIM);
    float var  = ps2[0] * (1.0f/DIM) - mean*mean;
    float inv = rsqrtf(var + 1e-5f);
    u16* orow = out + (size_t)row*DIM;
    orow[t]     = f2b((v0 - mean)*inv*g[t]     + bt[t]);
    orow[t+256] = f2b((v1 - mean)*inv*g[t+256] + bt[t+256]);
}

// ---------------- transpose+convert: src f32 [R][C] -> dst bf16 [C][R] ----------------
__global__ void transp_kernel(const float* __restrict__ src, u16* __restrict__ dst,
                              int R, int C) {
    __shared__ float tile[32][33];
    int c0 = blockIdx.x*32, r0 = blockIdx.y*32;
    int tx = threadIdx.x & 31, ty = threadIdx.x >> 5;   // 32 x 8
    #pragma unroll
    for (int ii = 0; ii < 4; ii++)
        tile[ty + ii*8][tx] = src[(size_t)(r0 + ty + ii*8)*C + c0 + tx];
    __syncthreads();
    #pragma unroll
    for (int ii = 0; ii < 4; ii++)
        dst[(size_t)(c0 + ty + ii*8)*R + r0 + tx] = f2b(tile[tx][ty + ii*8]);
}

// ---------------- bf16 MFMA GEMM: out = op((A@W^T' + bias)*scale) [+res] ----------------
// A bf16 [M][K]; WT bf16 [N][K]; 128x128 tile, BK=64, 4 waves each 64x64.
template<int OUTBF, int RELU, int HASRES>
__global__ __launch_bounds__(256) void mfma_gemm(
    const u16* __restrict__ A, const u16* __restrict__ WT,
    const float* __restrict__ bias, const float* __restrict__ res,
    float* __restrict__ Cf, u16* __restrict__ Cb,
    int M, int N, int K, float scale)
{
    __shared__ __align__(16) u16 a_lds[128*64];
    __shared__ __align__(16) u16 b_lds[128*64];
    int row0 = blockIdx.x*128, col0 = blockIdx.y*128;
    int tid = threadIdx.x, w = tid>>6, l = tid&63;
    int lg = l>>4, lc = l&15;
    int wr = (w>>1)*64, wc = (w&1)*64;
    f32x4 acc[4][4];
    #pragma unroll
    for (int m = 0; m < 4; m++)
        #pragma unroll
        for (int n = 0; n < 4; n++) { f32x4 z = {0.f,0.f,0.f,0.f}; acc[m][n] = z; }

    for (int k0 = 0; k0 < K; k0 += 64) {
        // stage A,B tiles (128x64 bf16 each) with XOR swizzle: slot = base ^ ((row&7)<<4)
        #pragma unroll
        for (int p = 0; p < 4; p++) {
            int e = p*256 + tid;
            int r = e >> 3, c16 = e & 7;
            int ldso = r*128 + ((c16*16) ^ ((r&7)<<4));
            int ra = row0 + r; if (ra > M-1) ra = M-1;
            s16x8 av = *(const s16x8*)(A + (size_t)ra*K + k0 + c16*8);
            *(s16x8*)((char*)a_lds + ldso) = av;
            s16x8 bv = *(const s16x8*)(WT + (size_t)(col0 + r)*K + k0 + c16*8);
            *(s16x8*)((char*)b_lds + ldso) = bv;
        }
        __syncthreads();
        #pragma unroll
        for (int ks = 0; ks < 2; ks++) {
            int cb = (ks*64 + lg*16) ^ ((l&7)<<4);
            s16x8 af[4], bfr[4];
            #pragma unroll
            for (int m = 0; m < 4; m++)
                af[m] = *(const s16x8*)((const char*)a_lds + (wr + m*16 + lc)*128 + cb);
            #pragma unroll
            for (int n = 0; n < 4; n++)
                bfr[n] = *(const s16x8*)((const char*)b_lds + (wc + n*16 + lc)*128 + cb);
            #pragma unroll
            for (int m = 0; m < 4; m++)
                #pragma unroll
                for (int n = 0; n < 4; n++)
                    acc[m][n] = __builtin_amdgcn_mfma_f32_16x16x32_bf16(af[m], bfr[n], acc[m][n], 0, 0, 0);
        }
        __syncthreads();
    }
    // epilogue: D row = 4*(l>>4)+reg, col = l&15
    #pragma unroll
    for (int m = 0; m < 4; m++) {
        #pragma unroll
        for (int r = 0; r < 4; r++) {
            int row = row0 + wr + m*16 + lg*4 + r;
            if (row >= M) continue;
            #pragma unroll
            for (int n = 0; n < 4; n++) {
                int col = col0 + wc + n*16 + lc;
                float v = (acc[m][n][r] + bias[col]) * scale;
                if (RELU) v = fmaxf(v, 0.f);
                size_t idx = (size_t)row*N + col;
                if (OUTBF) {
                    Cb[idx] = f2b(v);
                } else {
                    if (HASRES) v += res[idx];
                    Cf[idx] = v;
                }
            }
        }
    }
}

// ---------------- qx/qy: qx[bh,pi,t] = q[b,NE+pi,h,:]·x_emb[t,:]  (bf16 out) ----------------
__global__ void qxy_kernel(const u16* __restrict__ q, const float* __restrict__ x_emb,
                           const float* __restrict__ y_emb, u16* __restrict__ qx,
                           u16* __restrict__ qy) {
    int id = blockIdx.x;                  // (b*NH+h)*S2 + pi
    int pi = id & (S2-1);
    int bh = id >> 10;
    int b = bh >> 3, hh = bh & 7;
    __shared__ float qs[HD];
    if (threadIdx.x < HD)
        qs[threadIdx.x] = b2f(q[((size_t)(b*SS + NE + pi))*DIM + hh*HD + threadIdx.x]);
    __syncthreads();
    int t = threadIdx.x & 63;
    const float* emb = (threadIdx.x < 64) ? x_emb : y_emb;
    float acc = 0.f;
    #pragma unroll 8
    for (int d = 0; d < HD; d++) acc += qs[d] * emb[t*HD + d];
    u16* dst = (threadIdx.x < 64) ? qx : qy;
    dst[(size_t)id*64 + t] = f2b(acc);
}

// ---------------- qp: qp0/1[bh,i] = q[b,i,h,:]·pad0/1 (f32 out) ----------------
__global__ void qp_kernel(const u16* __restrict__ q, const float* __restrict__ pad0,
                          const float* __restrict__ pad1, float* __restrict__ qp0,
                          float* __restrict__ qp1) {
    int idx = blockIdx.x * blockDim.x + threadIdx.x;
    if (idx >= BB*NH*SS) return;
    int i = idx % SS; int bh = idx / SS; int b = bh >> 3, hh = bh & 7;
    const u16* qr = q + ((size_t)(b*SS + i))*DIM + hh*HD;
    float a0 = 0.f, a1 = 0.f;
    #pragma unroll 8
    for (int d = 0; d < HD; d++) { float qv = b2f(qr[d]); a0 += qv*pad0[d]; a1 += qv*pad1[d]; }
    qp0[idx] = a0; qp1[idx] = a1;
}

// ---------------- flash-style MFMA attention ----------------
// block: 4 waves x 16 q-rows = 64 q-rows; key tiles of 64.
#define KT 64
#define NKT 17
#define NQT 17
__global__ __launch_bounds__(256) void attn_mfma(
    const u16* __restrict__ q, const u16* __restrict__ k, const u16* __restrict__ v,
    const u16* __restrict__ qx, const u16* __restrict__ qy,
    const float* __restrict__ qp0, const float* __restrict__ qp1,
    u16* __restrict__ o)
{
    __shared__ __align__(16) u16 Vt[64][72];        // V^T: [d][key], pad->stride 144B
    __shared__ __align__(16) u16 Pl[4][16][72];     // per-wave P: [q][key]
    int qt = blockIdx.x, bh = blockIdx.y;
    int b = bh >> 3, hh = bh & 7;
    int tid = threadIdx.x, w = tid>>6, l = tid&63;
    int lg = l>>4, lc = l&15;
    int i0w = qt*64 + w*16;

    const s16x8 zs = {0,0,0,0,0,0,0,0};

    // Q A-fragments: row = lc, k = lg*8 (+32 for ks=1)
    s16x8 qa0 = zs, qa1 = zs;
    {
        int qrow = i0w + lc;
        if (qrow < SS) {
            const u16* qp = q + ((size_t)(b*SS + qrow))*DIM + hh*HD + lg*8;
            qa0 = *(const s16x8*)qp;
            qa1 = *(const s16x8*)(qp + 32);
        }
    }

    float m_[4] = {-1e30f, -1e30f, -1e30f, -1e30f};
    float l_[4] = {0.f, 0.f, 0.f, 0.f};
    f32x4 oacc[4];
    #pragma unroll
    for (int f = 0; f < 4; f++) { f32x4 z = {0.f,0.f,0.f,0.f}; oacc[f] = z; }

    int skey = tid & 63, sd0 = (tid >> 6) * 16;     // V staging map

    for (int kt = 0; kt < NKT; kt++) {
        int j0 = kt * KT;
        // ---- stage V^T (all waves) ----
        {
            int key = j0 + skey;
            uint4 v0 = {0,0,0,0}, v1 = {0,0,0,0};
            if (key < SS) {
                const uint4* vp = (const uint4*)(v + ((size_t)(b*SS + key))*DIM + hh*HD + sd0);
                v0 = vp[0]; v1 = vp[1];
            }
            const u16* pv = (const u16*)&v0;
            #pragma unroll
            for (int jj = 0; jj < 8; jj++) Vt[sd0 + jj][skey] = pv[jj];
            pv = (const u16*)&v1;
            #pragma unroll
            for (int jj = 0; jj < 8; jj++) Vt[sd0 + 8 + jj][skey] = pv[jj];
        }
        // ---- QK^T: K B-frags direct from global ----
        f32x4 s[4];
        #pragma unroll
        for (int f = 0; f < 4; f++) {
            int krow = j0 + f*16 + lc;
            s16x8 kb0 = zs, kb1 = zs;
            if (krow < SS) {
                const u16* kp = k + ((size_t)(b*SS + krow))*DIM + hh*HD + lg*8;
                kb0 = *(const s16x8*)kp;
                kb1 = *(const s16x8*)(kp + 32);
            }
            f32x4 z = {0.f,0.f,0.f,0.f};
            z = __builtin_amdgcn_mfma_f32_16x16x32_bf16(qa0, kb0, z, 0, 0, 0);
            s[f] = __builtin_amdgcn_mfma_f32_16x16x32_bf16(qa1, kb1, s[f] = z, 0, 0, 0);
        }
        __syncthreads();   // Vt staged; prev-iter readers done via end-of-loop barrier

        // ---- bias + online softmax ----
        #pragma unroll
        for (int r = 0; r < 4; r++) {
            int i = i0w + lg*4 + r;
            #pragma unroll
            for (int f = 0; f < 4; f++) {
                int j = j0 + f*16 + lc;
                float sv = s[f][r];
                if (j >= SS) sv = -1e30f;
                else if (i < SS) {
                    float bias;
                    if (i < NE) bias = (j < NE) ? qp0[bh*SS + i] : qp1[bh*SS + i];
                    else if (j < NE) bias = qp1[bh*SS + i];
                    else {
                        int pi = i - NE, pj = j - NE;
                        int xd = (pj & 31) - (pi & 31) + 32;
                        int yd = (pj >> 5) - (pi >> 5) + 32;
                        size_t base = ((size_t)bh*S2 + pi)*64;
                        bias = b2f(qx[base + xd]) + b2f(qy[base + yd]);
                    }
                    sv += bias;
                }
                s[f][r] = sv;
            }
            float t4 = fmaxf(fmaxf(s[0][r], s[1][r]), fmaxf(s[2][r], s[3][r]));
            t4 = fmaxf(t4, __shfl_xor(t4, 1));
            t4 = fmaxf(t4, __shfl_xor(t4, 2));
            t4 = fmaxf(t4, __shfl_xor(t4, 4));
            t4 = fmaxf(t4, __shfl_xor(t4, 8));
            float mn = fmaxf(m_[r], t4);
            float sc = __expf(m_[r] - mn);
            m_[r] = mn;
            float rs = 0.f;
            #pragma unroll
            for (int f = 0; f < 4; f++) {
                float p = __expf(s[f][r] - mn);
                s[f][r] = p;
                rs += p;
            }
            rs += __shfl_xor(rs, 1); rs += __shfl_xor(rs, 2);
            rs += __shfl_xor(rs, 4); rs += __shfl_xor(rs, 8);
            l_[r] = l_[r]*sc + rs;
            #pragma unroll
            for (int f = 0; f < 4; f++) oacc[f][r] *= sc;
        }
        // ---- P -> LDS (wave-private), then PV ----
        #pragma unroll
        for (int r = 0; r < 4; r++)
            #pragma unroll
            for (int f = 0; f < 4; f++)
                Pl[w][lg*4 + r][f*16 + lc] = f2b(s[f][r]);
        #pragma unroll
        for (int ks = 0; ks < 2; ks++) {
            s16x8 pa = *(const s16x8*)&Pl[w][lc][ks*32 + lg*8];
            #pragma unroll
            for (int f = 0; f < 4; f++) {
                s16x8 vb = *(const s16x8*)&Vt[f*16 + lc][ks*32 + lg*8];
                oacc[f] = __builtin_amdgcn_mfma_f32_16x16x32_bf16(pa, vb, oacc[f], 0, 0, 0);
            }
        }
        __syncthreads();   // all PV reads of Vt done before next stage
    }
    // ---- write O (bf16) ----
    #pragma unroll
    for (int r = 0; r < 4; r++) {
        int i = i0w + lg*4 + r;
        if (i >= SS) continue;
        float inv = 1.0f / l_[r];
        #pragma unroll
        for (int f = 0; f < 4; f++)
            o[((size_t)(b*SS + i))*DIM + hh*HD + f*16 + lc] = f2b(oacc[f][r] * inv);
    }
}

// ---------------- classifier (f32 h) ----------------
__global__ void cls_kernel(const float* __restrict__ h, const float* __restrict__ Wc,
                           const float* __restrict__ bc, float* __restrict__ out) {
    int g = blockIdx.x*4 + (threadIdx.x >> 6);
    int lane = threadIdx.x & 63;
    if (g >= BB*S2) return;
    int b = g >> 10, p = g & 1023;
    const float* hr = h + ((size_t)(b*SS + NE + p))*DIM;
    float a0 = 0.f, a1 = 0.f;
    for (int d = lane; d < DIM; d += 64) {
        float hv = hr[d];
        a0 += hv * Wc[d*NC + 0];
        a1 += hv * Wc[d*NC + 1];
    }
    for (int off = 32; off; off >>= 1) { a0 += __shfl_down(a0, off); a1 += __shfl_down(a1, off); }
    if (lane == 0) {
        out[((size_t)(b*NC + 0))*S2 + p] = a0 + bc[0];
        out[((size_t)(b*NC + 1))*S2 + p] = a1 + bc[1];
    }
}

extern "C" void kernel_launch(void* const* d_in, const int* in_sizes, int n_in,
                              void* d_out, int out_size, void* d_ws, size_t ws_size,
                              hipStream_t stream) {
    const float* x      = (const float*)d_in[0];
    const float* patches= (const float*)d_in[1];
    const float* We     = (const float*)d_in[2];
    const float* be     = (const float*)d_in[3];
    const float* x_emb  = (const float*)d_in[4];
    const float* y_emb  = (const float*)d_in[5];
    const float* pad0   = (const float*)d_in[6];
    const float* pad1   = (const float*)d_in[7];
    const float* Wq     = (const float*)d_in[8];
    const float* bq     = (const float*)d_in[9];
    const float* Wk     = (const float*)d_in[10];
    const float* bk     = (const float*)d_in[11];
    const float* Wv     = (const float*)d_in[12];
    const float* bv     = (const float*)d_in[13];
    const float* Wo     = (const float*)d_in[14];
    const float* bo     = (const float*)d_in[15];
    const float* ln1_g  = (const float*)d_in[16];
    const float* ln1_b  = (const float*)d_in[17];
    const float* ln2_g  = (const float*)d_in[18];
    const float* ln2_b  = (const float*)d_in[19];
    const float* W1     = (const float*)d_in[20];
    const float* b1     = (const float*)d_in[21];
    const float* W2     = (const float*)d_in[22];
    const float* b2     = (const float*)d_in[23];
    const float* Wc     = (const float*)d_in[24];
    const float* bc     = (const float*)d_in[25];
    float* out = (float*)d_out;

    float* ws = (float*)d_ws;
    const size_t MD = (size_t)MM*DIM;            // 4,210,688
    float* h   = ws;                             // MD f32
    u16*  hn   = (u16*)(ws + MD);                // MD bf16
    u16*  qkvo = (u16*)(ws + MD + MD/2);         // 4*MD bf16; t aliases all 4
    u16*  qb = qkvo;
    u16*  kb = qkvo + MD;
    u16*  vb = qkvo + 2*MD;
    u16*  ob = qkvo + 3*MD;
    u16*  tb = qkvo;
    float* after = ws + 3*MD + MD/2;
    u16*  qx = (u16*)after;                      // 64*1024*64 bf16
    u16*  qy = qx + (size_t)4194304;
    float* qp0 = after + 4194304;                // (2*4,194,304 u16 = 4,194,304 floats)
    float* qp1 = qp0 + 65792;
    u16*  wt  = (u16*)(qp1 + 65792);             // 6,291,456 bf16

    const size_t WL = 3145728;   // per-layer wt block (u16)

    // ---- weight transpose+convert (every launch; graph-safe) ----
    for (int l = 0; l < LL; l++) {
        u16* base = wt + (size_t)l*WL;
        transp_kernel<<<dim3(16,16), 256, 0, stream>>>(Wq + (size_t)l*DIM*DIM, base + 0,       DIM, DIM);
        transp_kernel<<<dim3(16,16), 256, 0, stream>>>(Wk + (size_t)l*DIM*DIM, base + 262144,  DIM, DIM);
        transp_kernel<<<dim3(16,16), 256, 0, stream>>>(Wv + (size_t)l*DIM*DIM, base + 524288,  DIM, DIM);
        transp_kernel<<<dim3(16,16), 256, 0, stream>>>(Wo + (size_t)l*DIM*DIM, base + 786432,  DIM, DIM);
        transp_kernel<<<dim3(64,16), 256, 0, stream>>>(W1 + (size_t)l*DIM*FFD, base + 1048576, DIM, FFD);
        transp_kernel<<<dim3(16,64), 256, 0, stream>>>(W2 + (size_t)l*FFD*DIM, base + 2097152, FFD, DIM);
    }

    embed_kernel<<<MM, 256, 0, stream>>>(x, patches, We, be, h);

    dim3 g512(65, 4);    // M-tiles x N-tiles for N=512
    dim3 gFF (65, 16);   // N=2048

    for (int l = 0; l < LL; l++) {
        u16* base = wt + (size_t)l*WL;
        const float* bql = bq + (size_t)l*DIM;
        const float* bkl = bk + (size_t)l*DIM;
        const float* bvl = bv + (size_t)l*DIM;
        const float* bol = bo + (size_t)l*DIM;
        const float* b1l = b1 + (size_t)l*FFD;
        const float* b2l = b2 + (size_t)l*DIM;

        ln_kernel<<<MM, 256, 0, stream>>>(h, hn, ln1_g + l*DIM, ln1_b + l*DIM);
        mfma_gemm<1,0,0><<<g512, 256, 0, stream>>>(hn, base + 0,      bql, nullptr, nullptr, qb, MM, DIM, DIM, 0.125f);
        mfma_gemm<1,0,0><<<g512, 256, 0, stream>>>(hn, base + 262144, bkl, nullptr, nullptr, kb, MM, DIM, DIM, 1.f);
        mfma_gemm<1,0,0><<<g512, 256, 0, stream>>>(hn, base + 524288, bvl, nullptr, nullptr, vb, MM, DIM, DIM, 1.f);
        qxy_kernel<<<BB*NH*S2, 128, 0, stream>>>(qb, x_emb, y_emb, qx, qy);
        qp_kernel<<<(BB*NH*SS + 255)/256, 256, 0, stream>>>(qb, pad0, pad1, qp0, qp1);
        attn_mfma<<<dim3(NQT, BB*NH), 256, 0, stream>>>(qb, kb, vb, qx, qy, qp0, qp1, ob);
        mfma_gemm<0,0,1><<<g512, 256, 0, stream>>>(ob, base + 786432, bol, h, h, nullptr, MM, DIM, DIM, 1.f);
        ln_kernel<<<MM, 256, 0, stream>>>(h, hn, ln2_g + l*DIM, ln2_b + l*DIM);
        mfma_gemm<1,1,0><<<gFF, 256, 0, stream>>>(hn, base + 1048576, b1l, nullptr, nullptr, tb, MM, FFD, DIM, 1.f);
        mfma_gemm<0,0,1><<<g512, 256, 0, stream>>>(tb, base + 2097152, b2l, h, h, nullptr, MM, DIM, FFD, 1.f);
    }

    cls_kernel<<<(BB*S2)/4, 256, 0, stream>>>(h, Wc, bc, out);
}

// Round 4
// 1213.726 us; speedup vs baseline: 7.8713x; 1.2232x over previous
//
#include <hip/hip_runtime.h>
#include <hip/hip_bf16.h>

#define DS 32
#define DIM 512
#define NH 8
#define HD 64
#define NE 4
#define NC 2
#define BB 8
#define LL 2
#define FFD 2048
#define S2 1024
#define SS 1028
#define MM (BB*SS)          // 8224 rows
#define KE 160              // extended K dim for bias-folded attention

typedef __attribute__((ext_vector_type(8))) short s16x8;
typedef __attribute__((ext_vector_type(4))) float f32x4;
typedef unsigned short u16;

__device__ __forceinline__ u16 f2b(float f) {
    __hip_bfloat16 h = __float2bfloat16(f);
    return *reinterpret_cast<u16*>(&h);
}
__device__ __forceinline__ float b2f(u16 u) {
    __hip_bfloat16 h;
    *reinterpret_cast<u16*>(&h) = u;
    return __bfloat162float(h);
}

// ---------------- embed ----------------
__global__ void embed_kernel(const float* __restrict__ x, const float* __restrict__ patches,
                             const float* __restrict__ We, const float* __restrict__ be,
                             float* __restrict__ h) {
    int row = blockIdx.x;
    int b = row / SS, i = row % SS;
    float* hr = h + (size_t)row * DIM;
    if (i < NE) {
        const float* xr = x + (size_t)b*NE*DIM + (size_t)i*DIM;
        for (int d = threadIdx.x; d < DIM; d += blockDim.x) hr[d] = xr[d];
    } else {
        int p = i - NE;
        float c0 = patches[(size_t)b*3*S2 + 0*S2 + p];
        float c1 = patches[(size_t)b*3*S2 + 1*S2 + p];
        float c2 = patches[(size_t)b*3*S2 + 2*S2 + p];
        for (int d = threadIdx.x; d < DIM; d += blockDim.x)
            hr[d] = be[d] + c0*We[d] + c1*We[DIM+d] + c2*We[2*DIM+d];
    }
}

// ---------------- layernorm: f32 in -> bf16 out ----------------
__global__ void ln_kernel(const float* __restrict__ in, u16* __restrict__ out,
                          const float* __restrict__ g, const float* __restrict__ bt) {
    int row = blockIdx.x;
    const float* xr = in + (size_t)row*DIM;
    int t = threadIdx.x;
    float v0 = xr[t], v1 = xr[t+256];
    float s = v0 + v1, s2 = v0*v0 + v1*v1;
    for (int off = 32; off; off >>= 1) { s += __shfl_down(s, off); s2 += __shfl_down(s2, off); }
    __shared__ float ps[4], ps2[4];
    int wid = t >> 6, lane = t & 63;
    if (lane == 0) { ps[wid] = s; ps2[wid] = s2; }
    __syncthreads();
    if (t == 0) { ps[0] = ps[0]+ps[1]+ps[2]+ps[3]; ps2[0] = ps2[0]+ps2[1]+ps2[2]+ps2[3]; }
    __syncthreads();
    float mean = ps[0] * (1.0f/DIM);
    float var  = ps2[0] * (1.0f/DIM) - mean*mean;
    float inv = rsqrtf(var + 1e-5f);
    u16* orow = out + (size_t)row*DIM;
    orow[t]     = f2b((v0 - mean)*inv*g[t]     + bt[t]);
    orow[t+256] = f2b((v1 - mean)*inv*g[t+256] + bt[t+256]);
}

// ---------------- transpose+convert: src f32 [R][C] -> dst bf16 [C][R] ----------------
__global__ void transp_kernel(const float* __restrict__ src, u16* __restrict__ dst,
                              int R, int C) {
    __shared__ float tile[32][33];
    int c0 = blockIdx.x*32, r0 = blockIdx.y*32;
    int tx = threadIdx.x & 31, ty = threadIdx.x >> 5;   // 32 x 8
    #pragma unroll
    for (int ii = 0; ii < 4; ii++)
        tile[ty + ii*8][tx] = src[(size_t)(r0 + ty + ii*8)*C + c0 + tx];
    __syncthreads();
    #pragma unroll
    for (int ii = 0; ii < 4; ii++)
        dst[(size_t)(c0 + ty + ii*8)*R + r0 + tx] = f2b(tile[tx][ty + ii*8]);
}

__global__ void cat_bias_kernel(const float* __restrict__ bq, const float* __restrict__ bk,
                                const float* __restrict__ bv, float* __restrict__ out) {
    int t = blockIdx.x*256 + threadIdx.x;
    if (t >= 1536) return;
    out[t] = (t < 512) ? bq[t] : (t < 1024 ? bk[t-512] : bv[t-1024]);
}

// ---------------- bf16 MFMA GEMM, reg-prefetch double buffer ----------------
// MODE: 0 = f32 out + residual, 1 = bf16 out (RELU opt), 2 = qkv split (Cb=q, kd, vd)
template<int MODE, int RELU>
__global__ __launch_bounds__(256) void mfma_gemm(
    const u16* __restrict__ A, const u16* __restrict__ WT,
    const float* __restrict__ bias, const float* __restrict__ res,
    float* __restrict__ Cf, u16* __restrict__ Cb,
    u16* __restrict__ kd, u16* __restrict__ vd,
    int M, int N, int K)
{
    __shared__ __align__(16) u16 a_lds[128*64];
    __shared__ __align__(16) u16 b_lds[128*64];
    int row0 = blockIdx.x*128, col0 = blockIdx.y*128;
    int tid = threadIdx.x, w = tid>>6, l = tid&63;
    int lg = l>>4, lc = l&15;
    int wr = (w>>1)*64, wc = (w&1)*64;
    f32x4 acc[4][4];
    #pragma unroll
    for (int m = 0; m < 4; m++)
        #pragma unroll
        for (int n = 0; n < 4; n++) { f32x4 z = {0.f,0.f,0.f,0.f}; acc[m][n] = z; }

    // staging element mapping (per p): r = e>>3, c16 = e&7
    s16x8 ar[4], br[4];
    #pragma unroll
    for (int p = 0; p < 4; p++) {
        int e = p*256 + tid;
        int r = e >> 3, c16 = e & 7;
        int ra = row0 + r; if (ra > M-1) ra = M-1;
        ar[p] = *(const s16x8*)(A  + (size_t)ra*K + c16*8);
        br[p] = *(const s16x8*)(WT + (size_t)(col0 + r)*K + c16*8);
    }

    for (int k0 = 0; k0 < K; k0 += 64) {
        #pragma unroll
        for (int p = 0; p < 4; p++) {
            int e = p*256 + tid;
            int r = e >> 3, c16 = e & 7;
            int ldso = r*128 + ((c16*16) ^ ((r&7)<<4));
            *(s16x8*)((char*)a_lds + ldso) = ar[p];
            *(s16x8*)((char*)b_lds + ldso) = br[p];
        }
        __syncthreads();
        int kn = k0 + 64;
        if (kn < K) {
            #pragma unroll
            for (int p = 0; p < 4; p++) {
                int e = p*256 + tid;
                int r = e >> 3, c16 = e & 7;
                int ra = row0 + r; if (ra > M-1) ra = M-1;
                ar[p] = *(const s16x8*)(A  + (size_t)ra*K + kn + c16*8);
                br[p] = *(const s16x8*)(WT + (size_t)(col0 + r)*K + kn + c16*8);
            }
        }
        #pragma unroll
        for (int ks = 0; ks < 2; ks++) {
            int cb = (ks*64 + lg*16) ^ ((l&7)<<4);
            s16x8 af[4], bfr[4];
            #pragma unroll
            for (int m = 0; m < 4; m++)
                af[m] = *(const s16x8*)((const char*)a_lds + (wr + m*16 + lc)*128 + cb);
            #pragma unroll
            for (int n = 0; n < 4; n++)
                bfr[n] = *(const s16x8*)((const char*)b_lds + (wc + n*16 + lc)*128 + cb);
            #pragma unroll
            for (int m = 0; m < 4; m++)
                #pragma unroll
                for (int n = 0; n < 4; n++)
                    acc[m][n] = __builtin_amdgcn_mfma_f32_16x16x32_bf16(af[m], bfr[n], acc[m][n], 0, 0, 0);
        }
        __syncthreads();
    }
    // epilogue: D row = 4*lg+reg, col = lc
    #pragma unroll
    for (int m = 0; m < 4; m++) {
        #pragma unroll
        for (int r = 0; r < 4; r++) {
            int row = row0 + wr + m*16 + lg*4 + r;
            if (row >= M) continue;
            #pragma unroll
            for (int n = 0; n < 4; n++) {
                int col = col0 + wc + n*16 + lc;
                float v = acc[m][n][r] + bias[col];
                if (MODE == 2) {
                    int which = col >> 9, c2 = col & 511;
                    if (which == 0) v *= 0.125f;
                    u16* dst = (which == 0) ? Cb : (which == 1 ? kd : vd);
                    dst[(size_t)row*512 + c2] = f2b(v);
                } else if (MODE == 1) {
                    if (RELU) v = fmaxf(v, 0.f);
                    Cb[(size_t)row*N + col] = f2b(v);
                } else {
                    Cf[(size_t)row*N + col] = v + res[(size_t)row*N + col];
                }
            }
        }
    }
}

// ---------------- qx/qy: qx[bh,pi,t] = q[b,NE+pi,h,:]·x_emb[t,:]  (bf16 out) ----------------
__global__ void qxy_kernel(const u16* __restrict__ q, const float* __restrict__ x_emb,
                           const float* __restrict__ y_emb, u16* __restrict__ qx,
                           u16* __restrict__ qy) {
    int id = blockIdx.x;                  // (b*NH+h)*S2 + pi
    int pi = id & (S2-1);
    int bh = id >> 10;
    int b = bh >> 3, hh = bh & 7;
    __shared__ float qs[HD];
    if (threadIdx.x < HD)
        qs[threadIdx.x] = b2f(q[((size_t)(b*SS + NE + pi))*DIM + hh*HD + threadIdx.x]);
    __syncthreads();
    int t = threadIdx.x & 63;
    const float* emb = (threadIdx.x < 64) ? x_emb : y_emb;
    float acc = 0.f;
    #pragma unroll 8
    for (int d = 0; d < HD; d++) acc += qs[d] * emb[t*HD + d];
    u16* dst = (threadIdx.x < 64) ? qx : qy;
    dst[(size_t)id*64 + t] = f2b(acc);
}

// ---------------- qp: qp0/1[bh,i] = q[b,i,h,:]·pad0/1 (f32 out) ----------------
__global__ void qp_kernel(const u16* __restrict__ q, const float* __restrict__ pad0,
                          const float* __restrict__ pad1, float* __restrict__ qp0,
                          float* __restrict__ qp1) {
    int idx = blockIdx.x * blockDim.x + threadIdx.x;
    if (idx >= BB*NH*SS) return;
    int i = idx % SS; int bh = idx / SS; int b = bh >> 3, hh = bh & 7;
    const u16* qr = q + ((size_t)(b*SS + i))*DIM + hh*HD;
    float a0 = 0.f, a1 = 0.f;
    #pragma unroll 8
    for (int d = 0; d < HD; d++) { float qv = b2f(qr[d]); a0 += qv*pad0[d]; a1 += qv*pad1[d]; }
    qp0[idx] = a0; qp1[idx] = a1;
}

// ---------------- Q_ext build: [bh][i][160] ----------------
// dims [0,64)=q  [64,96)=qx window  [96,128)=qy window  128=p1 129=p2  rest 0
__global__ void qext_kernel(const u16* __restrict__ qb, const u16* __restrict__ qx,
                            const u16* __restrict__ qy, const float* __restrict__ qp0,
                            const float* __restrict__ qp1, u16* __restrict__ Qe) {
    int id = blockIdx.x*256 + threadIdx.x;
    if (id >= BB*NH*SS*KE) return;
    int t = id % KE;
    int row = id / KE;                // bh*SS + i
    int bh = row / SS, i = row % SS;
    int b = bh >> 3, hh = bh & 7;
    u16 val = 0;
    if (t < 64) val = qb[((size_t)(b*SS + i))*DIM + hh*HD + t];
    else if (i >= NE) {
        int pi = i - NE;
        if (t < 96)       { int ci = pi & 31; val = qx[((size_t)bh*S2 + pi)*64 + (t-64) - ci + 32]; }
        else if (t < 128) { int ri = pi >> 5; val = qy[((size_t)bh*S2 + pi)*64 + (t-96) - ri + 32]; }
        else if (t == 128) val = f2b(qp1[bh*SS + i]);
    } else {
        if (t == 128)      val = f2b(qp0[bh*SS + i]);
        else if (t == 129) val = f2b(qp1[bh*SS + i]);
    }
    Qe[id] = val;
}

// ---------------- K_ext build: [bh][j][160] ----------------
__global__ void kext_kernel(const u16* __restrict__ kb, u16* __restrict__ Ke) {
    int id = blockIdx.x*256 + threadIdx.x;
    if (id >= BB*NH*SS*KE) return;
    int t = id % KE;
    int row = id / KE;
    int bh = row / SS, j = row % SS;
    int b = bh >> 3, hh = bh & 7;
    const u16 ONE = 0x3F80;
    u16 val = 0;
    if (t < 64) val = kb[((size_t)(b*SS + j))*DIM + hh*HD + t];
    else if (j >= NE) {
        int pj = j - NE;
        if (t < 96)       { if ((pj & 31) == t-64) val = ONE; }
        else if (t < 128) { if ((pj >> 5) == t-96) val = ONE; }
        else if (t == 129) val = ONE;
    } else if (t == 128) val = ONE;
    Ke[id] = val;
}

// ---------------- flash-style MFMA attention, bias folded into K_ext ----------------
#define KT 64
#define NKT 17
#define NQT 17
__global__ __launch_bounds__(256) void attn_mfma(
    const u16* __restrict__ Qe, const u16* __restrict__ Ke,
    const u16* __restrict__ v, u16* __restrict__ o)
{
    __shared__ __align__(16) u16 Kl[64*192];        // 64 rows x 384B (swizzled), 24.5 KB
    __shared__ __align__(16) u16 Vt[64][72];        // V^T [d][key]
    __shared__ __align__(16) u16 Pl[4][16][72];     // per-wave P
    int qt = blockIdx.x, bh = blockIdx.y;
    int b = bh >> 3, hh = bh & 7;
    int tid = threadIdx.x, w = tid>>6, l = tid&63;
    int lg = l>>4, lc = l&15;
    int i0w = qt*64 + w*16;
    const s16x8 zs = {0,0,0,0,0,0,0,0};

    // Q_ext A-frags (row = lc, k chunk = lg*8 within each 32-dim step)
    s16x8 qa[5];
    {
        int qrow = i0w + lc; if (qrow > SS-1) qrow = SS-1;
        const u16* qp = Qe + ((size_t)bh*SS + qrow)*KE + lg*8;
        #pragma unroll
        for (int ks = 0; ks < 5; ks++) qa[ks] = *(const s16x8*)(qp + ks*32);
    }

    float m_[4] = {-1e30f, -1e30f, -1e30f, -1e30f};
    float l_[4] = {0.f, 0.f, 0.f, 0.f};
    f32x4 oacc[4];
    #pragma unroll
    for (int f = 0; f < 4; f++) { f32x4 z = {0.f,0.f,0.f,0.f}; oacc[f] = z; }

    int skey = tid & 63, sd0 = (tid >> 6) * 16;     // V staging map

    for (int kt2 = 0; kt2 < NKT; kt2++) {
        int j0 = kt2 * KT;
        // ---- stage K_ext tile: 64 rows x 20 16B-units, XOR swizzle both sides ----
        #pragma unroll
        for (int p = 0; p < 5; p++) {
            int e = p*256 + tid;
            int row = e / 20, u = e - row*20;
            int j = j0 + row;
            s16x8 kv = zs;
            if (j < SS) kv = *(const s16x8*)(Ke + ((size_t)bh*SS + j)*KE + u*8);
            *(s16x8*)((char*)Kl + row*384 + ((u ^ (row&7)) << 4)) = kv;
        }
        // ---- stage V^T ----
        {
            int key = j0 + skey;
            uint4 v0 = {0,0,0,0}, v1 = {0,0,0,0};
            if (key < SS) {
                const uint4* vp = (const uint4*)(v + ((size_t)(b*SS + key))*DIM + hh*HD + sd0);
                v0 = vp[0]; v1 = vp[1];
            }
            const u16* pv = (const u16*)&v0;
            #pragma unroll
            for (int jj = 0; jj < 8; jj++) Vt[sd0 + jj][skey] = pv[jj];
            pv = (const u16*)&v1;
            #pragma unroll
            for (int jj = 0; jj < 8; jj++) Vt[sd0 + 8 + jj][skey] = pv[jj];
        }
        __syncthreads();

        // ---- QK_ext^T: 5 k-steps x 4 key-frags ----
        f32x4 s[4];
        #pragma unroll
        for (int f = 0; f < 4; f++) { f32x4 z = {0.f,0.f,0.f,0.f}; s[f] = z; }
        #pragma unroll
        for (int ks = 0; ks < 5; ks++)
            #pragma unroll
            for (int f = 0; f < 4; f++) {
                int row = f*16 + lc;
                s16x8 kb2 = *(const s16x8*)((const char*)Kl + row*384 + ((((ks<<2)+lg) ^ (row&7)) << 4));
                s[f] = __builtin_amdgcn_mfma_f32_16x16x32_bf16(qa[ks], kb2, s[f], 0, 0, 0);
            }

        // ---- online softmax (no bias code; only tail mask) ----
        #pragma unroll
        for (int r = 0; r < 4; r++) {
            #pragma unroll
            for (int f = 0; f < 4; f++) {
                int j = j0 + f*16 + lc;
                if (j >= SS) s[f][r] = -1e30f;
            }
            float t4 = fmaxf(fmaxf(s[0][r], s[1][r]), fmaxf(s[2][r], s[3][r]));
            t4 = fmaxf(t4, __shfl_xor(t4, 1));
            t4 = fmaxf(t4, __shfl_xor(t4, 2));
            t4 = fmaxf(t4, __shfl_xor(t4, 4));
            t4 = fmaxf(t4, __shfl_xor(t4, 8));
            float mn = fmaxf(m_[r], t4);
            float sc = __expf(m_[r] - mn);
            m_[r] = mn;
            float rs = 0.f;
            #pragma unroll
            for (int f = 0; f < 4; f++) {
                float p = __expf(s[f][r] - mn);
                s[f][r] = p;
                rs += p;
            }
            rs += __shfl_xor(rs, 1); rs += __shfl_xor(rs, 2);
            rs += __shfl_xor(rs, 4); rs += __shfl_xor(rs, 8);
            l_[r] = l_[r]*sc + rs;
            #pragma unroll
            for (int f = 0; f < 4; f++) oacc[f][r] *= sc;
        }
        // ---- P -> LDS (wave-private), then PV ----
        #pragma unroll
        for (int r = 0; r < 4; r++)
            #pragma unroll
            for (int f = 0; f < 4; f++)
                Pl[w][lg*4 + r][f*16 + lc] = f2b(s[f][r]);
        #pragma unroll
        for (int ks = 0; ks < 2; ks++) {
            s16x8 pa = *(const s16x8*)&Pl[w][lc][ks*32 + lg*8];
            #pragma unroll
            for (int f = 0; f < 4; f++) {
                s16x8 vb = *(const s16x8*)&Vt[f*16 + lc][ks*32 + lg*8];
                oacc[f] = __builtin_amdgcn_mfma_f32_16x16x32_bf16(pa, vb, oacc[f], 0, 0, 0);
            }
        }
        __syncthreads();
    }
    // ---- write O (bf16) ----
    #pragma unroll
    for (int r = 0; r < 4; r++) {
        int i = i0w + lg*4 + r;
        if (i >= SS) continue;
        float inv = 1.0f / l_[r];
        #pragma unroll
        for (int f = 0; f < 4; f++)
            o[((size_t)(b*SS + i))*DIM + hh*HD + f*16 + lc] = f2b(oacc[f][r] * inv);
    }
}

// ---------------- classifier ----------------
__global__ void cls_kernel(const float* __restrict__ h, const float* __restrict__ Wc,
                           const float* __restrict__ bc, float* __restrict__ out) {
    int g = blockIdx.x*4 + (threadIdx.x >> 6);
    int lane = threadIdx.x & 63;
    if (g >= BB*S2) return;
    int b = g >> 10, p = g & 1023;
    const float* hr = h + ((size_t)(b*SS + NE + p))*DIM;
    float a0 = 0.f, a1 = 0.f;
    for (int d = lane; d < DIM; d += 64) {
        float hv = hr[d];
        a0 += hv * Wc[d*NC + 0];
        a1 += hv * Wc[d*NC + 1];
    }
    for (int off = 32; off; off >>= 1) { a0 += __shfl_down(a0, off); a1 += __shfl_down(a1, off); }
    if (lane == 0) {
        out[((size_t)(b*NC + 0))*S2 + p] = a0 + bc[0];
        out[((size_t)(b*NC + 1))*S2 + p] = a1 + bc[1];
    }
}

extern "C" void kernel_launch(void* const* d_in, const int* in_sizes, int n_in,
                              void* d_out, int out_size, void* d_ws, size_t ws_size,
                              hipStream_t stream) {
    const float* x      = (const float*)d_in[0];
    const float* patches= (const float*)d_in[1];
    const float* We     = (const float*)d_in[2];
    const float* be     = (const float*)d_in[3];
    const float* x_emb  = (const float*)d_in[4];
    const float* y_emb  = (const float*)d_in[5];
    const float* pad0   = (const float*)d_in[6];
    const float* pad1   = (const float*)d_in[7];
    const float* Wq     = (const float*)d_in[8];
    const float* bq     = (const float*)d_in[9];
    const float* Wk     = (const float*)d_in[10];
    const float* bk     = (const float*)d_in[11];
    const float* Wv     = (const float*)d_in[12];
    const float* bv     = (const float*)d_in[13];
    const float* Wo     = (const float*)d_in[14];
    const float* bo     = (const float*)d_in[15];
    const float* ln1_g  = (const float*)d_in[16];
    const float* ln1_b  = (const float*)d_in[17];
    const float* ln2_g  = (const float*)d_in[18];
    const float* ln2_b  = (const float*)d_in[19];
    const float* W1     = (const float*)d_in[20];
    const float* b1     = (const float*)d_in[21];
    const float* W2     = (const float*)d_in[22];
    const float* b2     = (const float*)d_in[23];
    const float* Wc     = (const float*)d_in[24];
    const float* bc     = (const float*)d_in[25];
    float* out = (float*)d_out;

    float* ws = (float*)d_ws;
    const size_t MD = (size_t)MM*DIM;                  // 4,210,688
    float* h  = ws;                                    // MD f32
    u16* hn   = (u16*)(ws + MD);                       // MD bf16
    u16* qb   = (u16*)(ws + MD + MD/2);                // 4x MD bf16 (q,k,v,o); tb aliases
    u16* kb   = qb + MD;
    u16* vb   = qb + 2*MD;
    u16* ob   = qb + 3*MD;
    u16* tb   = qb;
    const size_t EXT = (size_t)BB*NH*SS*KE;            // 10,526,720 u16
    u16* Qe   = (u16*)(ws + 3*MD + MD/2);
    u16* Ke   = Qe + EXT;
    float* after = ws + 3*MD + MD/2 + EXT;             // EXT u16 x2 = EXT floats
    u16* qx   = (u16*)after;                           // 4,194,304 u16 each
    u16* qy   = qx + (size_t)4194304;
    float* qp0 = after + 4194304;
    float* qp1 = qp0 + 65792;
    float* bqkv = qp1 + 65792;                         // 1536 f32
    u16* wt   = (u16*)(bqkv + 1536);                   // 6,291,456 u16

    const size_t WL = 3145728;   // per-layer transposed-weight block (u16)

    // ---- weight transpose+convert (graph-safe, every launch) ----
    for (int l = 0; l < LL; l++) {
        u16* base = wt + (size_t)l*WL;
        transp_kernel<<<dim3(16,16), 256, 0, stream>>>(Wq + (size_t)l*DIM*DIM, base + 0,        DIM, DIM);
        transp_kernel<<<dim3(16,16), 256, 0, stream>>>(Wk + (size_t)l*DIM*DIM, base + 262144,   DIM, DIM);
        transp_kernel<<<dim3(16,16), 256, 0, stream>>>(Wv + (size_t)l*DIM*DIM, base + 524288,   DIM, DIM);
        transp_kernel<<<dim3(16,16), 256, 0, stream>>>(Wo + (size_t)l*DIM*DIM, base + 786432,   DIM, DIM);
        transp_kernel<<<dim3(64,16), 256, 0, stream>>>(W1 + (size_t)l*DIM*FFD, base + 1048576,  DIM, FFD);
        transp_kernel<<<dim3(16,64), 256, 0, stream>>>(W2 + (size_t)l*FFD*DIM, base + 2097152,  FFD, DIM);
    }

    embed_kernel<<<MM, 256, 0, stream>>>(x, patches, We, be, h);

    dim3 gQKV(65, 12);   // N=1536
    dim3 g512(65, 4);    // N=512
    dim3 gFF (65, 16);   // N=2048
    const int extBlocks = (int)((EXT + 255) / 256);

    for (int l = 0; l < LL; l++) {
        u16* base = wt + (size_t)l*WL;
        cat_bias_kernel<<<6, 256, 0, stream>>>(bq + (size_t)l*DIM, bk + (size_t)l*DIM, bv + (size_t)l*DIM, bqkv);
        ln_kernel<<<MM, 256, 0, stream>>>(h, hn, ln1_g + l*DIM, ln1_b + l*DIM);
        mfma_gemm<2,0><<<gQKV, 256, 0, stream>>>(hn, base, bqkv, nullptr, nullptr, qb, kb, vb, MM, 1536, DIM);
        qxy_kernel<<<BB*NH*S2, 128, 0, stream>>>(qb, x_emb, y_emb, qx, qy);
        qp_kernel<<<(BB*NH*SS + 255)/256, 256, 0, stream>>>(qb, pad0, pad1, qp0, qp1);
        qext_kernel<<<extBlocks, 256, 0, stream>>>(qb, qx, qy, qp0, qp1, Qe);
        kext_kernel<<<extBlocks, 256, 0, stream>>>(kb, Ke);
        attn_mfma<<<dim3(NQT, BB*NH), 256, 0, stream>>>(Qe, Ke, vb, ob);
        mfma_gemm<0,0><<<g512, 256, 0, stream>>>(ob, base + 786432, bo + (size_t)l*DIM, h, h, nullptr, nullptr, nullptr, MM, DIM, DIM);
        ln_kernel<<<MM, 256, 0, stream>>>(h, hn, ln2_g + l*DIM, ln2_b + l*DIM);
        mfma_gemm<1,1><<<gFF, 256, 0, stream>>>(hn, base + 1048576, b1 + (size_t)l*FFD, nullptr, nullptr, tb, nullptr, nullptr, MM, FFD, DIM);
        mfma_gemm<0,0><<<g512, 256, 0, stream>>>(tb, base + 2097152, b2 + (size_t)l*DIM, h, h, nullptr, nullptr, nullptr, MM, DIM, FFD);
    }

    cls_kernel<<<(BB*S2)/4, 256, 0, stream>>>(h, Wc, bc, out);
}

// Round 6
// 724.609 us; speedup vs baseline: 13.1845x; 1.6750x over previous
//
#include <hip/hip_runtime.h>
#include <hip/hip_bf16.h>

#define DS 32
#define DIM 512
#define NH 8
#define HD 64
#define NE 4
#define NC 2
#define BB 8
#define LL 2
#define FFD 2048
#define S2 1024
#define SS 1028
#define MM (BB*SS)          // 8224 rows
#define KE 160              // extended K dim for bias-folded attention
#define EXT ((size_t)BB*NH*SS*KE)

typedef __attribute__((ext_vector_type(8))) short s16x8;
typedef __attribute__((ext_vector_type(4))) float f32x4;
typedef unsigned short u16;

__device__ __forceinline__ u16 f2b(float f) {
    __hip_bfloat16 h = __float2bfloat16(f);
    return *reinterpret_cast<u16*>(&h);
}
__device__ __forceinline__ float b2f(u16 u) {
    __hip_bfloat16 h;
    *reinterpret_cast<u16*>(&h) = u;
    return __bfloat162float(h);
}

// ---------------- embed ----------------
__global__ void embed_kernel(const float* __restrict__ x, const float* __restrict__ patches,
                             const float* __restrict__ We, const float* __restrict__ be,
                             float* __restrict__ h) {
    int row = blockIdx.x;
    int b = row / SS, i = row % SS;
    float* hr = h + (size_t)row * DIM;
    if (i < NE) {
        const float* xr = x + (size_t)b*NE*DIM + (size_t)i*DIM;
        for (int d = threadIdx.x; d < DIM; d += blockDim.x) hr[d] = xr[d];
    } else {
        int p = i - NE;
        float c0 = patches[(size_t)b*3*S2 + 0*S2 + p];
        float c1 = patches[(size_t)b*3*S2 + 1*S2 + p];
        float c2 = patches[(size_t)b*3*S2 + 2*S2 + p];
        for (int d = threadIdx.x; d < DIM; d += blockDim.x)
            hr[d] = be[d] + c0*We[d] + c1*We[DIM+d] + c2*We[2*DIM+d];
    }
}

// ---------------- layernorm: f32 in -> bf16 out ----------------
__global__ void ln_kernel(const float* __restrict__ in, u16* __restrict__ out,
                          const float* __restrict__ g, const float* __restrict__ bt) {
    int row = blockIdx.x;
    const float* xr = in + (size_t)row*DIM;
    int t = threadIdx.x;
    float v0 = xr[t], v1 = xr[t+256];
    float s = v0 + v1, s2 = v0*v0 + v1*v1;
    for (int off = 32; off; off >>= 1) { s += __shfl_down(s, off); s2 += __shfl_down(s2, off); }
    __shared__ float ps[4], ps2[4];
    int wid = t >> 6, lane = t & 63;
    if (lane == 0) { ps[wid] = s; ps2[wid] = s2; }
    __syncthreads();
    if (t == 0) { ps[0] = ps[0]+ps[1]+ps[2]+ps[3]; ps2[0] = ps2[0]+ps2[1]+ps2[2]+ps2[3]; }
    __syncthreads();
    float mean = ps[0] * (1.0f/DIM);
    float var  = ps2[0] * (1.0f/DIM) - mean*mean;
    float inv = rsqrtf(var + 1e-5f);
    u16* orow = out + (size_t)row*DIM;
    orow[t]     = f2b((v0 - mean)*inv*g[t]     + bt[t]);
    orow[t+256] = f2b((v1 - mean)*inv*g[t+256] + bt[t+256]);
}

// ---------------- transpose+convert: src f32 [R][C] -> dst bf16 [C][R] ----------------
__global__ void transp_kernel(const float* __restrict__ src, u16* __restrict__ dst,
                              int R, int C) {
    __shared__ float tile[32][33];
    int c0 = blockIdx.x*32, r0 = blockIdx.y*32;
    int tx = threadIdx.x & 31, ty = threadIdx.x >> 5;   // 32 x 8
    #pragma unroll
    for (int ii = 0; ii < 4; ii++)
        tile[ty + ii*8][tx] = src[(size_t)(r0 + ty + ii*8)*C + c0 + tx];
    __syncthreads();
    #pragma unroll
    for (int ii = 0; ii < 4; ii++)
        dst[(size_t)(c0 + ty + ii*8)*R + r0 + tx] = f2b(tile[tx][ty + ii*8]);
}

__global__ void cat_bias_kernel(const float* __restrict__ bq, const float* __restrict__ bk,
                                const float* __restrict__ bv, float* __restrict__ out) {
    int t = blockIdx.x*256 + threadIdx.x;
    if (t >= 1536) return;
    out[t] = (t < 512) ? bq[t] : (t < 1024 ? bk[t-512] : bv[t-1024]);
}

// ---------------- bf16 MFMA GEMM, reg-prefetch double buffer ----------------
// MODE: 0 = f32 out + residual, 1 = bf16 out (RELU opt), 2 = qkv split (Cb=q, kd, vd)
template<int MODE, int RELU>
__global__ __launch_bounds__(256) void mfma_gemm(
    const u16* __restrict__ A, const u16* __restrict__ WT,
    const float* __restrict__ bias, const float* __restrict__ res,
    float* __restrict__ Cf, u16* __restrict__ Cb,
    u16* __restrict__ kd, u16* __restrict__ vd,
    int M, int N, int K)
{
    __shared__ __align__(16) u16 a_lds[128*64];
    __shared__ __align__(16) u16 b_lds[128*64];
    int row0 = blockIdx.x*128, col0 = blockIdx.y*128;
    int tid = threadIdx.x, w = tid>>6, l = tid&63;
    int lg = l>>4, lc = l&15;
    int wr = (w>>1)*64, wc = (w&1)*64;
    f32x4 acc[4][4];
    #pragma unroll
    for (int m = 0; m < 4; m++)
        #pragma unroll
        for (int n = 0; n < 4; n++) { f32x4 z = {0.f,0.f,0.f,0.f}; acc[m][n] = z; }

    s16x8 ar[4], br[4];
    #pragma unroll
    for (int p = 0; p < 4; p++) {
        int e = p*256 + tid;
        int r = e >> 3, c16 = e & 7;
        int ra = row0 + r; if (ra > M-1) ra = M-1;
        ar[p] = *(const s16x8*)(A  + (size_t)ra*K + c16*8);
        br[p] = *(const s16x8*)(WT + (size_t)(col0 + r)*K + c16*8);
    }

    for (int k0 = 0; k0 < K; k0 += 64) {
        #pragma unroll
        for (int p = 0; p < 4; p++) {
            int e = p*256 + tid;
            int r = e >> 3, c16 = e & 7;
            int ldso = r*128 + ((c16*16) ^ ((r&7)<<4));
            *(s16x8*)((char*)a_lds + ldso) = ar[p];
            *(s16x8*)((char*)b_lds + ldso) = br[p];
        }
        __syncthreads();
        int kn = k0 + 64;
        if (kn < K) {
            #pragma unroll
            for (int p = 0; p < 4; p++) {
                int e = p*256 + tid;
                int r = e >> 3, c16 = e & 7;
                int ra = row0 + r; if (ra > M-1) ra = M-1;
                ar[p] = *(const s16x8*)(A  + (size_t)ra*K + kn + c16*8);
                br[p] = *(const s16x8*)(WT + (size_t)(col0 + r)*K + kn + c16*8);
            }
        }
        #pragma unroll
        for (int ks = 0; ks < 2; ks++) {
            int cb = (ks*64 + lg*16) ^ ((l&7)<<4);
            s16x8 af[4], bfr[4];
            #pragma unroll
            for (int m = 0; m < 4; m++)
                af[m] = *(const s16x8*)((const char*)a_lds + (wr + m*16 + lc)*128 + cb);
            #pragma unroll
            for (int n = 0; n < 4; n++)
                bfr[n] = *(const s16x8*)((const char*)b_lds + (wc + n*16 + lc)*128 + cb);
            #pragma unroll
            for (int m = 0; m < 4; m++)
                #pragma unroll
                for (int n = 0; n < 4; n++)
                    acc[m][n] = __builtin_amdgcn_mfma_f32_16x16x32_bf16(af[m], bfr[n], acc[m][n], 0, 0, 0);
        }
        __syncthreads();
    }
    #pragma unroll
    for (int m = 0; m < 4; m++) {
        #pragma unroll
        for (int r = 0; r < 4; r++) {
            int row = row0 + wr + m*16 + lg*4 + r;
            if (row >= M) continue;
            #pragma unroll
            for (int n = 0; n < 4; n++) {
                int col = col0 + wc + n*16 + lc;
                float v = acc[m][n][r] + bias[col];
                if (MODE == 2) {
                    int which = col >> 9, c2 = col & 511;
                    if (which == 0) v *= 0.125f;
                    u16* dst = (which == 0) ? Cb : (which == 1 ? kd : vd);
                    dst[(size_t)row*512 + c2] = f2b(v);
                } else if (MODE == 1) {
                    if (RELU) v = fmaxf(v, 0.f);
                    Cb[(size_t)row*N + col] = f2b(v);
                } else {
                    Cf[(size_t)row*N + col] = v + res[(size_t)row*N + col];
                }
            }
        }
    }
}

// ---------------- qp: qp0/1[bh,i] = q[b,i,h,:]·pad0/1 (f32 out) ----------------
__global__ void qp_kernel(const u16* __restrict__ q, const float* __restrict__ pad0,
                          const float* __restrict__ pad1, float* __restrict__ qp0,
                          float* __restrict__ qp1) {
    int idx = blockIdx.x * blockDim.x + threadIdx.x;
    if (idx >= BB*NH*SS) return;
    int i = idx % SS; int bh = idx / SS; int b = bh >> 3, hh = bh & 7;
    const u16* qr = q + ((size_t)(b*SS + i))*DIM + hh*HD;
    float a0 = 0.f, a1 = 0.f;
    #pragma unroll 8
    for (int d = 0; d < HD; d++) { float qv = b2f(qr[d]); a0 += qv*pad0[d]; a1 += qv*pad1[d]; }
    qp0[idx] = a0; qp1[idx] = a1;
}

// ---------------- Q_ext skeleton (vectorized, 8 u16/thread) ----------------
// dims [0,64)=q  [64,128)=0 (windows filled by qxy_mfma)  128/129=pad scalars  rest 0
__global__ void qext_kernel(const u16* __restrict__ qb, const float* __restrict__ qp0,
                            const float* __restrict__ qp1, u16* __restrict__ Qe) {
    size_t id = (size_t)blockIdx.x*256 + threadIdx.x;     // unit index (8 u16 each)
    if (id >= EXT/8) return;
    int u = (int)(id % 20);
    size_t row = id / 20;                                  // bh*SS + i
    int bh = (int)(row / SS), i = (int)(row - (size_t)bh*SS);
    int b = bh >> 3, hh = bh & 7;
    s16x8 val = {0,0,0,0,0,0,0,0};
    if (u < 8) {
        val = *(const s16x8*)(qb + ((size_t)(b*SS + i))*DIM + hh*HD + u*8);
    } else if (u == 16) {
        float v128 = (i < NE) ? qp0[bh*SS + i] : qp1[bh*SS + i];
        float v129 = (i < NE) ? qp1[bh*SS + i] : 0.f;
        val[0] = (short)f2b(v128);
        val[1] = (short)f2b(v129);
    }
    *(s16x8*)(Qe + row*KE + u*8) = val;
}

// ---------------- K_ext build (vectorized) ----------------
__global__ void kext_kernel(const u16* __restrict__ kb, u16* __restrict__ Ke) {
    size_t id = (size_t)blockIdx.x*256 + threadIdx.x;
    if (id >= EXT/8) return;
    int u = (int)(id % 20);
    size_t row = id / 20;
    int bh = (int)(row / SS), j = (int)(row - (size_t)bh*SS);
    int b = bh >> 3, hh = bh & 7;
    const short ONE = 0x3F80;
    s16x8 val = {0,0,0,0,0,0,0,0};
    if (u < 8) {
        val = *(const s16x8*)(kb + ((size_t)(b*SS + j))*DIM + hh*HD + u*8);
    } else {
        int pj = j - NE, cj = pj & 31, rj = pj >> 5;
        #pragma unroll
        for (int e = 0; e < 8; e++) {
            int t = u*8 + e;
            short v = 0;
            if (j >= NE) {
                if (t < 96)       { if (cj == t-64) v = ONE; }
                else if (t < 128) { if (rj == t-96) v = ONE; }
                else if (t == 129) v = ONE;
            } else if (t == 128) v = ONE;
            val[e] = v;
        }
    }
    *(s16x8*)(Ke + row*KE + u*8) = val;
}

// ---------------- qx/qy via MFMA, windows scattered directly into Q_ext ----------------
// grid (8 pi-tiles, 64 bh); out cols tau: [0,64)=x_emb dot, [64,128)=y_emb dot
__global__ __launch_bounds__(256) void qxy_mfma(
    const u16* __restrict__ q, const float* __restrict__ x_emb,
    const float* __restrict__ y_emb, u16* __restrict__ Qe)
{
    int tile = blockIdx.x, bh = blockIdx.y;
    int b = bh >> 3, hh = bh & 7;
    int tid = threadIdx.x, w = tid>>6, l = tid&63;
    int lg = l>>4, lc = l&15;
    int wr = (w>>1)*64, wc = (w&1)*64;
    int pi0 = tile*128;

    f32x4 acc[4][4];
    #pragma unroll
    for (int m = 0; m < 4; m++)
        #pragma unroll
        for (int n = 0; n < 4; n++) { f32x4 z = {0.f,0.f,0.f,0.f}; acc[m][n] = z; }

    s16x8 af[4][2];
    #pragma unroll
    for (int m = 0; m < 4; m++) {
        int pi = pi0 + wr + m*16 + lc;
        const u16* qp = q + ((size_t)(b*SS + NE + pi))*DIM + hh*HD + lg*8;
        af[m][0] = *(const s16x8*)qp;
        af[m][1] = *(const s16x8*)(qp + 32);
    }
    s16x8 bf[4][2];
    #pragma unroll
    for (int n = 0; n < 4; n++) {
        int tau = wc + n*16 + lc;
        const float* ep = (tau < 64) ? (x_emb + (size_t)tau*HD) : (y_emb + (size_t)(tau-64)*HD);
        #pragma unroll
        for (int ks = 0; ks < 2; ks++) {
            const float* e8 = ep + ks*32 + lg*8;
            s16x8 bv;
            #pragma unroll
            for (int t2 = 0; t2 < 8; t2++) bv[t2] = (short)f2b(e8[t2]);
            bf[n][ks] = bv;
        }
    }
    #pragma unroll
    for (int ks = 0; ks < 2; ks++)
        #pragma unroll
        for (int m = 0; m < 4; m++)
            #pragma unroll
            for (int n = 0; n < 4; n++)
                acc[m][n] = __builtin_amdgcn_mfma_f32_16x16x32_bf16(af[m][ks], bf[n][ks], acc[m][n], 0, 0, 0);

    // epilogue: scatter windows into Qe[row][64+c] (x) and [96+c] (y)
    #pragma unroll
    for (int m = 0; m < 4; m++) {
        #pragma unroll
        for (int r = 0; r < 4; r++) {
            int pi = pi0 + wr + m*16 + lg*4 + r;
            int ci = pi & 31, ri = pi >> 5;
            size_t rowbase = ((size_t)bh*SS + NE + pi)*KE;
            #pragma unroll
            for (int n = 0; n < 4; n++) {
                int tau = wc + n*16 + lc;
                float v = acc[m][n][r];
                if (tau < 64) {
                    int c = tau + ci - 32;
                    if (c >= 0 && c < 32) Qe[rowbase + 64 + c] = f2b(v);
                } else {
                    int c = (tau - 64) + ri - 32;
                    if (c >= 0 && c < 32) Qe[rowbase + 96 + c] = f2b(v);
                }
            }
        }
    }
}

// ---------------- flash-style MFMA attention, bias folded into K_ext ----------------
#define KT 64
#define NKT 17
#define NQT 17
__global__ __launch_bounds__(256) void attn_mfma(
    const u16* __restrict__ Qe, const u16* __restrict__ Ke,
    const u16* __restrict__ v, u16* __restrict__ o)
{
    __shared__ __align__(16) u16 Kl[64*192];        // 64 rows x 384B (swizzled)
    __shared__ __align__(16) u16 Vt[64][72];        // V^T [d][key]
    __shared__ __align__(16) u16 Pl[4][16][72];     // per-wave P
    int qt = blockIdx.x, bh = blockIdx.y;
    int b = bh >> 3, hh = bh & 7;
    int tid = threadIdx.x, w = tid>>6, l = tid&63;
    int lg = l>>4, lc = l&15;
    int i0w = qt*64 + w*16;
    const s16x8 zs = {0,0,0,0,0,0,0,0};

    s16x8 qa[5];
    {
        int qrow = i0w + lc; if (qrow > SS-1) qrow = SS-1;
        const u16* qp = Qe + ((size_t)bh*SS + qrow)*KE + lg*8;
        #pragma unroll
        for (int ks = 0; ks < 5; ks++) qa[ks] = *(const s16x8*)(qp + ks*32);
    }

    float m_[4] = {-1e30f, -1e30f, -1e30f, -1e30f};
    float l_[4] = {0.f, 0.f, 0.f, 0.f};
    f32x4 oacc[4];
    #pragma unroll
    for (int f = 0; f < 4; f++) { f32x4 z = {0.f,0.f,0.f,0.f}; oacc[f] = z; }

    int skey = tid & 63, sd0 = (tid >> 6) * 16;

    for (int kt2 = 0; kt2 < NKT; kt2++) {
        int j0 = kt2 * KT;
        #pragma unroll
        for (int p = 0; p < 5; p++) {
            int e = p*256 + tid;
            int row = e / 20, u = e - row*20;
            int j = j0 + row;
            s16x8 kv = zs;
            if (j < SS) kv = *(const s16x8*)(Ke + ((size_t)bh*SS + j)*KE + u*8);
            *(s16x8*)((char*)Kl + row*384 + ((u ^ (row&7)) << 4)) = kv;
        }
        {
            int key = j0 + skey;
            uint4 v0 = {0,0,0,0}, v1 = {0,0,0,0};
            if (key < SS) {
                const uint4* vp = (const uint4*)(v + ((size_t)(b*SS + key))*DIM + hh*HD + sd0);
                v0 = vp[0]; v1 = vp[1];
            }
            const u16* pv = (const u16*)&v0;
            #pragma unroll
            for (int jj = 0; jj < 8; jj++) Vt[sd0 + jj][skey] = pv[jj];
            pv = (const u16*)&v1;
            #pragma unroll
            for (int jj = 0; jj < 8; jj++) Vt[sd0 + 8 + jj][skey] = pv[jj];
        }
        __syncthreads();

        f32x4 s[4];
        #pragma unroll
        for (int f = 0; f < 4; f++) { f32x4 z = {0.f,0.f,0.f,0.f}; s[f] = z; }
        #pragma unroll
        for (int ks = 0; ks < 5; ks++)
            #pragma unroll
            for (int f = 0; f < 4; f++) {
                int row = f*16 + lc;
                s16x8 kb2 = *(const s16x8*)((const char*)Kl + row*384 + ((((ks<<2)+lg) ^ (row&7)) << 4));
                s[f] = __builtin_amdgcn_mfma_f32_16x16x32_bf16(qa[ks], kb2, s[f], 0, 0, 0);
            }

        #pragma unroll
        for (int r = 0; r < 4; r++) {
            #pragma unroll
            for (int f = 0; f < 4; f++) {
                int j = j0 + f*16 + lc;
                if (j >= SS) s[f][r] = -1e30f;
            }
            float t4 = fmaxf(fmaxf(s[0][r], s[1][r]), fmaxf(s[2][r], s[3][r]));
            t4 = fmaxf(t4, __shfl_xor(t4, 1));
            t4 = fmaxf(t4, __shfl_xor(t4, 2));
            t4 = fmaxf(t4, __shfl_xor(t4, 4));
            t4 = fmaxf(t4, __shfl_xor(t4, 8));
            float mn = fmaxf(m_[r], t4);
            float sc = __expf(m_[r] - mn);
            m_[r] = mn;
            float rs = 0.f;
            #pragma unroll
            for (int f = 0; f < 4; f++) {
                float p = __expf(s[f][r] - mn);
                s[f][r] = p;
                rs += p;
            }
            rs += __shfl_xor(rs, 1); rs += __shfl_xor(rs, 2);
            rs += __shfl_xor(rs, 4); rs += __shfl_xor(rs, 8);
            l_[r] = l_[r]*sc + rs;
            #pragma unroll
            for (int f = 0; f < 4; f++) oacc[f][r] *= sc;
        }
        #pragma unroll
        for (int r = 0; r < 4; r++)
            #pragma unroll
            for (int f = 0; f < 4; f++)
                Pl[w][lg*4 + r][f*16 + lc] = f2b(s[f][r]);
        #pragma unroll
        for (int ks = 0; ks < 2; ks++) {
            s16x8 pa = *(const s16x8*)&Pl[w][lc][ks*32 + lg*8];
            #pragma unroll
            for (int f = 0; f < 4; f++) {
                s16x8 vb = *(const s16x8*)&Vt[f*16 + lc][ks*32 + lg*8];
                oacc[f] = __builtin_amdgcn_mfma_f32_16x16x32_bf16(pa, vb, oacc[f], 0, 0, 0);
            }
        }
        __syncthreads();
    }
    #pragma unroll
    for (int r = 0; r < 4; r++) {
        int i = i0w + lg*4 + r;
        if (i >= SS) continue;
        float inv = 1.0f / l_[r];
        #pragma unroll
        for (int f = 0; f < 4; f++)
            o[((size_t)(b*SS + i))*DIM + hh*HD + f*16 + lc] = f2b(oacc[f][r] * inv);
    }
}

// ---------------- classifier ----------------
__global__ void cls_kernel(const float* __restrict__ h, const float* __restrict__ Wc,
                           const float* __restrict__ bc, float* __restrict__ out) {
    int g = blockIdx.x*4 + (threadIdx.x >> 6);
    int lane = threadIdx.x & 63;
    if (g >= BB*S2) return;
    int b = g >> 10, p = g & 1023;
    const float* hr = h + ((size_t)(b*SS + NE + p))*DIM;
    float a0 = 0.f, a1 = 0.f;
    for (int d = lane; d < DIM; d += 64) {
        float hv = hr[d];
        a0 += hv * Wc[d*NC + 0];
        a1 += hv * Wc[d*NC + 1];
    }
    for (int off = 32; off; off >>= 1) { a0 += __shfl_down(a0, off); a1 += __shfl_down(a1, off); }
    if (lane == 0) {
        out[((size_t)(b*NC + 0))*S2 + p] = a0 + bc[0];
        out[((size_t)(b*NC + 1))*S2 + p] = a1 + bc[1];
    }
}

extern "C" void kernel_launch(void* const* d_in, const int* in_sizes, int n_in,
                              void* d_out, int out_size, void* d_ws, size_t ws_size,
                              hipStream_t stream) {
    const float* x      = (const float*)d_in[0];
    const float* patches= (const float*)d_in[1];
    const float* We     = (const float*)d_in[2];
    const float* be     = (const float*)d_in[3];
    const float* x_emb  = (const float*)d_in[4];
    const float* y_emb  = (const float*)d_in[5];
    const float* pad0   = (const float*)d_in[6];
    const float* pad1   = (const float*)d_in[7];
    const float* Wq     = (const float*)d_in[8];
    const float* bq     = (const float*)d_in[9];
    const float* Wk     = (const float*)d_in[10];
    const float* bk     = (const float*)d_in[11];
    const float* Wv     = (const float*)d_in[12];
    const float* bv     = (const float*)d_in[13];
    const float* Wo     = (const float*)d_in[14];
    const float* bo     = (const float*)d_in[15];
    const float* ln1_g  = (const float*)d_in[16];
    const float* ln1_b  = (const float*)d_in[17];
    const float* ln2_g  = (const float*)d_in[18];
    const float* ln2_b  = (const float*)d_in[19];
    const float* W1     = (const float*)d_in[20];
    const float* b1     = (const float*)d_in[21];
    const float* W2     = (const float*)d_in[22];
    const float* b2     = (const float*)d_in[23];
    const float* Wc     = (const float*)d_in[24];
    const float* bc     = (const float*)d_in[25];
    float* out = (float*)d_out;

    float* ws = (float*)d_ws;
    const size_t MD = (size_t)MM*DIM;                  // 4,210,688
    float* h  = ws;                                    // MD f32
    u16* hn   = (u16*)(ws + MD);                       // MD bf16
    u16* qb   = (u16*)(ws + MD + MD/2);                // 4x MD bf16 (q,k,v,o); tb aliases
    u16* kb   = qb + MD;
    u16* vb   = qb + 2*MD;
    u16* ob   = qb + 3*MD;
    u16* tb   = qb;
    u16* Qe   = (u16*)(ws + 3*MD + MD/2);              // EXT u16
    u16* Ke   = Qe + EXT;                              // EXT u16
    float* after = ws + 3*MD + MD/2 + EXT;             // Qe+Ke = 2*EXT u16 = EXT floats
    float* qp0 = after;
    float* qp1 = qp0 + 65792;
    float* bqkv = qp1 + 65792;                         // 1536 f32
    u16* wt   = (u16*)(bqkv + 1536);                   // 6,291,456 u16

    const size_t WL = 3145728;   // per-layer transposed-weight block (u16)

    for (int l = 0; l < LL; l++) {
        u16* base = wt + (size_t)l*WL;
        transp_kernel<<<dim3(16,16), 256, 0, stream>>>(Wq + (size_t)l*DIM*DIM, base + 0,        DIM, DIM);
        transp_kernel<<<dim3(16,16), 256, 0, stream>>>(Wk + (size_t)l*DIM*DIM, base + 262144,   DIM, DIM);
        transp_kernel<<<dim3(16,16), 256, 0, stream>>>(Wv + (size_t)l*DIM*DIM, base + 524288,   DIM, DIM);
        transp_kernel<<<dim3(16,16), 256, 0, stream>>>(Wo + (size_t)l*DIM*DIM, base + 786432,   DIM, DIM);
        transp_kernel<<<dim3(64,16), 256, 0, stream>>>(W1 + (size_t)l*DIM*FFD, base + 1048576,  DIM, FFD);
        transp_kernel<<<dim3(16,64), 256, 0, stream>>>(W2 + (size_t)l*FFD*DIM, base + 2097152,  FFD, DIM);
    }

    embed_kernel<<<MM, 256, 0, stream>>>(x, patches, We, be, h);

    dim3 gQKV(65, 12);   // N=1536
    dim3 g512(65, 4);    // N=512
    dim3 gFF (65, 16);   // N=2048
    const int extUnits = (int)(EXT / 8);
    const int extBlocks = (extUnits + 255) / 256;

    for (int l = 0; l < LL; l++) {
        u16* base = wt + (size_t)l*WL;
        cat_bias_kernel<<<6, 256, 0, stream>>>(bq + (size_t)l*DIM, bk + (size_t)l*DIM, bv + (size_t)l*DIM, bqkv);
        ln_kernel<<<MM, 256, 0, stream>>>(h, hn, ln1_g + l*DIM, ln1_b + l*DIM);
        mfma_gemm<2,0><<<gQKV, 256, 0, stream>>>(hn, base, bqkv, nullptr, nullptr, qb, kb, vb, MM, 1536, DIM);
        qp_kernel<<<(BB*NH*SS + 255)/256, 256, 0, stream>>>(qb, pad0, pad1, qp0, qp1);
        qext_kernel<<<extBlocks, 256, 0, stream>>>(qb, qp0, qp1, Qe);
        qxy_mfma<<<dim3(8, BB*NH), 256, 0, stream>>>(qb, x_emb, y_emb, Qe);
        kext_kernel<<<extBlocks, 256, 0, stream>>>(kb, Ke);
        attn_mfma<<<dim3(NQT, BB*NH), 256, 0, stream>>>(Qe, Ke, vb, ob);
        mfma_gemm<0,0><<<g512, 256, 0, stream>>>(ob, base + 786432, bo + (size_t)l*DIM, h, h, nullptr, nullptr, nullptr, MM, DIM, DIM);
        ln_kernel<<<MM, 256, 0, stream>>>(h, hn, ln2_g + l*DIM, ln2_b + l*DIM);
        mfma_gemm<1,1><<<gFF, 256, 0, stream>>>(hn, base + 1048576, b1 + (size_t)l*FFD, nullptr, nullptr, tb, nullptr, nullptr, MM, FFD, DIM);
        mfma_gemm<0,0><<<g512, 256, 0, stream>>>(tb, base + 2097152, b2 + (size_t)l*DIM, h, h, nullptr, nullptr, nullptr, MM, DIM, FFD);
    }

    cls_kernel<<<(BB*S2)/4, 256, 0, stream>>>(h, Wc, bc, out);
}